// Round 2
// baseline (379.308 us; speedup 1.0000x reference)
//
#include <hip/hip_runtime.h>
#include <hip/hip_bf16.h>

// FieldDecoder: B=16, 64x64 tokens, DO=768, kernel 16x16, stride 8, field 512x512
#define DIM      768
#define NPATCH   4096
#define BATCH    16
#define MROWS    (BATCH*NPATCH)   // 65536
#define NCOLS    256
#define FH       512
#define FW       512

typedef __attribute__((ext_vector_type(8))) short bf16x8;
typedef __attribute__((ext_vector_type(4))) float f32x4;

static __device__ __forceinline__ unsigned short f2bf(float f) {
    union { float f; unsigned int u; } v; v.f = f;
    unsigned int u = v.u;
    return (unsigned short)((u + 0x7FFFu + ((u >> 16) & 1u)) >> 16);
}
static __device__ __forceinline__ float bf2f(unsigned int u16) {
    union { unsigned int i; float f; } x; x.i = u16 << 16; return x.f;
}

// ---------------- kernel 0: weight fp32 -> bf16 ----------------
__global__ void wconv_kernel(const float* __restrict__ w, unsigned short* __restrict__ wb) {
    int i = blockIdx.x * blockDim.x + threadIdx.x;
    float4 v = ((const float4*)w)[i];
    unsigned int p0 = (unsigned)f2bf(v.x) | ((unsigned)f2bf(v.y) << 16);
    unsigned int p1 = (unsigned)f2bf(v.z) | ((unsigned)f2bf(v.w) << 16);
    ((uint2*)wb)[i] = make_uint2(p0, p1);
}

// ---------------- kernel 1: GEMM  C[M,256] = A[M,768](fp32->bf16) x Bw[256,768]^T ----------------
// 128x128 tile, BK=32, 256 thr (2x2 waves, each 64x64 via 4x4 MFMA 16x16x32).
// Software pipeline: next K-tile's A/B prefetched into registers during MFMA phase.
// Output proj is bf16 (halves write + gather read traffic).
#define BK 32
#define LSTR 40   // LDS row stride in bf16 units (80 B) -> 2-way bank alias only (free)

__global__ __launch_bounds__(256) void gemm_kernel(const float* __restrict__ A,
                                                   const unsigned short* __restrict__ Bw,
                                                   unsigned short* __restrict__ Cb) {
    __shared__ unsigned short sA[128 * LSTR];
    __shared__ unsigned short sB[128 * LSTR];

    const int tid = threadIdx.x;
    // XCD-aware swizzle: blocks r and r+8 of a 16-group share the same A m-stripe
    // and the same blockIdx%8 (-> same XCD under round-robin dispatch).
    const int lin  = blockIdx.x;           // 0..1023
    const int g    = lin >> 4;
    const int r16  = lin & 15;
    const int nblk = r16 >> 3;             // 0..1
    const int mblk = g * 8 + (r16 & 7);    // 0..511
    const int m0 = mblk * 128;
    const int n0 = nblk * 128;

    const int wave = tid >> 6;
    const int lane = tid & 63;
    const int wm = wave >> 1;
    const int wn = wave & 1;
    const int l15  = lane & 15;
    const int quad = lane >> 4;

    f32x4 acc[4][4] = {};

    const int arow = tid >> 3;   // 0..31
    const int ac4  = tid & 7;
    const int brow = tid >> 2;   // 0..63
    const int bc8  = tid & 3;

    const float*          aBase = A  + (size_t)(m0 + arow) * DIM + ac4 * 4;
    const unsigned short* bBase = Bw + (size_t)(n0 + brow) * DIM + bc8 * 8;

    float4 aReg[4];
    uint4  bReg[2];
    #pragma unroll
    for (int p = 0; p < 4; ++p) aReg[p] = *(const float4*)(aBase + (size_t)p * 32 * DIM);
    #pragma unroll
    for (int p = 0; p < 2; ++p) bReg[p] = *(const uint4*)(bBase + (size_t)p * 64 * DIM);

    #pragma unroll 1
    for (int k0 = 0; k0 < DIM; k0 += BK) {
        __syncthreads();   // previous iteration's ds_reads complete
        #pragma unroll
        for (int p = 0; p < 4; ++p) {
            const float4 v = aReg[p];
            unsigned int p0 = (unsigned)f2bf(v.x) | ((unsigned)f2bf(v.y) << 16);
            unsigned int p1 = (unsigned)f2bf(v.z) | ((unsigned)f2bf(v.w) << 16);
            *(uint2*)(&sA[(arow + p * 32) * LSTR + ac4 * 4]) = make_uint2(p0, p1);
        }
        #pragma unroll
        for (int p = 0; p < 2; ++p)
            *(uint4*)(&sB[(brow + p * 64) * LSTR + bc8 * 8]) = bReg[p];
        __syncthreads();

        if (k0 + BK < DIM) {   // prefetch next tile; latency hidden behind MFMA phase
            #pragma unroll
            for (int p = 0; p < 4; ++p)
                aReg[p] = *(const float4*)(aBase + (size_t)p * 32 * DIM + k0 + BK);
            #pragma unroll
            for (int p = 0; p < 2; ++p)
                bReg[p] = *(const uint4*)(bBase + (size_t)p * 64 * DIM + k0 + BK);
        }

        bf16x8 af[4], bfr[4];
        #pragma unroll
        for (int i = 0; i < 4; ++i)
            af[i] = *(const bf16x8*)(&sA[(wm * 64 + i * 16 + l15) * LSTR + quad * 8]);
        #pragma unroll
        for (int j = 0; j < 4; ++j)
            bfr[j] = *(const bf16x8*)(&sB[(wn * 64 + j * 16 + l15) * LSTR + quad * 8]);
        #pragma unroll
        for (int i = 0; i < 4; ++i)
            #pragma unroll
            for (int j = 0; j < 4; ++j)
                acc[i][j] = __builtin_amdgcn_mfma_f32_16x16x32_bf16(af[i], bfr[j], acc[i][j], 0, 0, 0);
    }

    // epilogue: C/D layout col = lane&15, row = quad*4 + reg; bf16 stores (L2 write-combines)
    #pragma unroll
    for (int i = 0; i < 4; ++i) {
        #pragma unroll
        for (int j = 0; j < 4; ++j) {
            const int col = n0 + wn * 64 + j * 16 + l15;
            #pragma unroll
            for (int rr = 0; rr < 4; ++rr) {
                const int row = m0 + wm * 64 + i * 16 + quad * 4 + rr;
                Cb[(size_t)row * NCOLS + col] = f2bf(acc[i][j][rr]);
            }
        }
    }
}

// ---------------- kernel 2: gather-mean, vectorized over 8-pixel w-groups ----------------
// Thread -> (b, ph, wg): outputs pw = 8*wg .. 8*wg+7.
// Contribution per h: patch (h,wg) dw=0..7 (16B) ; patch (h,wg-1) dw=8..15 (16B) if wg>0;
// wg==63 adds clamp extras (dw 8..15 of patch 63) to pixel 511 only.
__global__ void gather_kernel(const unsigned short* __restrict__ proj, float* __restrict__ out) {
    const int id  = blockIdx.x * blockDim.x + threadIdx.x;   // 16*512*64 = 524288
    const int b   = id >> 15;
    const int rem = id & 32767;
    const int ph  = rem >> 6;
    const int wg  = rem & 63;
    const unsigned short* p = proj + (size_t)b * (NPATCH * NCOLS);

    const int h_lo = (ph >= 8) ? ((ph - 8) >> 3) : 0;
    const int h_hi = ph >> 3;

    float s[8] = {0.f, 0.f, 0.f, 0.f, 0.f, 0.f, 0.f, 0.f};

    auto contrib = [&](int h, int dh) {
        const unsigned short* rowp = p + ((h * 64 + wg) * 256 + dh * 16);
        const uint4 c0 = *(const uint4*)rowp;
        const unsigned int w0[4] = {c0.x, c0.y, c0.z, c0.w};
        #pragma unroll
        for (int q = 0; q < 4; ++q) {
            s[2 * q]     += bf2f(w0[q] & 0xFFFFu);
            s[2 * q + 1] += bf2f(w0[q] >> 16);
        }
        if (wg > 0) {
            const uint4 cm = *(const uint4*)(p + ((h * 64 + wg - 1) * 256 + dh * 16 + 8));
            const unsigned int wm[4] = {cm.x, cm.y, cm.z, cm.w};
            #pragma unroll
            for (int q = 0; q < 4; ++q) {
                s[2 * q]     += bf2f(wm[q] & 0xFFFFu);
                s[2 * q + 1] += bf2f(wm[q] >> 16);
            }
        }
        if (wg == 63) {   // clamp extras: dw 8..15 of patch 63 -> pixel 511 (j==7)
            const uint4 ce = *(const uint4*)(rowp + 8);
            const unsigned int we[4] = {ce.x, ce.y, ce.z, ce.w};
            float e = 0.f;
            #pragma unroll
            for (int q = 0; q < 4; ++q)
                e += bf2f(we[q] & 0xFFFFu) + bf2f(we[q] >> 16);
            s[7] += e;
        }
    };

    for (int h = h_lo; h <= h_hi; ++h) contrib(h, ph - 8 * h);
    if (ph == 511) {
        #pragma unroll 1
        for (int dh = 8; dh < 16; ++dh) contrib(63, dh);
    }

    const float inv_ch = (ph < 8) ? 1.f : ((ph == 511) ? 0.1f : 0.5f);
    const float inv_cw = (wg == 0) ? 1.f : 0.5f;
    float f[8];
    #pragma unroll
    for (int j = 0; j < 8; ++j) f[j] = inv_ch * inv_cw;
    if (wg == 63) f[7] = inv_ch * 0.1f;

    float4 o0 = make_float4(s[0] * f[0], s[1] * f[1], s[2] * f[2], s[3] * f[3]);
    float4 o1 = make_float4(s[4] * f[4], s[5] * f[5], s[6] * f[6], s[7] * f[7]);
    float4* ob = (float4*)(out + (size_t)id * 8);
    ob[0] = o0;
    ob[1] = o1;
}

extern "C" void kernel_launch(void* const* d_in, const int* in_sizes, int n_in,
                              void* d_out, int out_size, void* d_ws, size_t ws_size,
                              hipStream_t stream) {
    const float* tgt    = (const float*)d_in[0];   // [16,4096,768] fp32
    const float* weight = (const float*)d_in[1];   // [16,16,768]  fp32
    float* out = (float*)d_out;                    // [16,512,512] fp32

    unsigned short* proj = (unsigned short*)d_ws;                                  // 32 MB bf16
    unsigned short* wbf  = (unsigned short*)((char*)d_ws + (size_t)MROWS * NCOLS * 2); // +384 KB

    wconv_kernel<<<192, 256, 0, stream>>>(weight, wbf);
    gemm_kernel<<<1024, 256, 0, stream>>>(tgt, wbf, proj);
    gather_kernel<<<(BATCH * FH * 64) / 256, 256, 0, stream>>>(proj, out);
}

// Round 3
// 371.853 us; speedup vs baseline: 1.0200x; 1.0200x over previous
//
#include <hip/hip_runtime.h>
#include <hip/hip_bf16.h>

// FieldDecoder: B=16, 64x64 tokens, DO=768, kernel 16x16, stride 8, field 512x512
#define DIM      768
#define NPATCH   4096
#define BATCH    16
#define MROWS    65536
#define NCOLS    256

typedef __attribute__((ext_vector_type(8))) short bf16x8;
typedef __attribute__((ext_vector_type(4))) float f32x4;
typedef unsigned short ushort_t;

static __device__ __forceinline__ unsigned short f2bf(float f) {
    union { float f; unsigned int u; } v; v.f = f;
    unsigned int u = v.u;
    return (unsigned short)((u + 0x7FFFu + ((u >> 16) & 1u)) >> 16);
}
static __device__ __forceinline__ float bf2f(unsigned int u16) {
    union { unsigned int i; float f; } x; x.i = u16 << 16; return x.f;
}

// ---------------- kernel 0: weight fp32 -> bf16 ----------------
__global__ void wconv_kernel(const float* __restrict__ w, unsigned short* __restrict__ wb) {
    int i = blockIdx.x * blockDim.x + threadIdx.x;
    float4 v = ((const float4*)w)[i];
    unsigned int p0 = (unsigned)f2bf(v.x) | ((unsigned)f2bf(v.y) << 16);
    unsigned int p1 = (unsigned)f2bf(v.z) | ((unsigned)f2bf(v.w) << 16);
    ((uint2*)wb)[i] = make_uint2(p0, p1);
}

// ---------------- kernel 1: GEMM  proj[M,256] = A[M,768](fp32->bf16) x Bw[256,768]^T ----------------
// Block: 256 thr = 4 waves. Block tile M=64 x N=256 (wave w -> cols w*64..+63), wave tile 64x64.
// A staged to LDS per K-half (49 KB, 3 blocks/CU); B read global->VGPR in MFMA layout (L2-resident).
// NO barriers in the K-loop -> waves free-run, B-load latency pipelined by the compiler.
#define KHALF 384
#define LSTRA 392    // bf16 row stride (384 + 8 pad): rows r,r+8 alias 2-way only (free)
#define CSTR  264    // epilogue LDS row stride

__global__ __launch_bounds__(256, 3) void gemm_kernel(const float* __restrict__ A,
                                                      const unsigned short* __restrict__ Bw,
                                                      unsigned short* __restrict__ Cb) {
    __shared__ unsigned short sA[64 * LSTRA];   // 50176 B (also reused for epilogue transpose)

    const int tid  = threadIdx.x;
    const int m0   = blockIdx.x * 64;
    const int wave = tid >> 6;
    const int lane = tid & 63;
    const int l15  = lane & 15;
    const int quad = lane >> 4;
    const int n0w  = wave * 64;

    f32x4 acc[4][4] = {};

    // staging decomposition: 4 threads per row, 24 float4 each
    const int srow = tid >> 2;
    const int su   = tid & 3;

    // loop-invariant fragment bases
    const unsigned short* bBase[4];
    #pragma unroll
    for (int j = 0; j < 4; ++j)
        bBase[j] = Bw + (size_t)(n0w + j * 16 + l15) * DIM + quad * 8;
    const unsigned short* aBase = sA + l15 * LSTRA + quad * 8;

    for (int half = 0; half < 2; ++half) {
        const int kbase = half * KHALF;
        __syncthreads();   // protect LDS from previous half's readers
        {
            const float* aRow = A + (size_t)(m0 + srow) * DIM + kbase + su * 4;
            unsigned short* dRow = sA + srow * LSTRA + su * 4;
            #pragma unroll
            for (int p = 0; p < 24; ++p) {
                float4 v = *(const float4*)(aRow + p * 16);
                unsigned int p0 = (unsigned)f2bf(v.x) | ((unsigned)f2bf(v.y) << 16);
                unsigned int p1 = (unsigned)f2bf(v.z) | ((unsigned)f2bf(v.w) << 16);
                *(uint2*)(dRow + p * 16) = make_uint2(p0, p1);
            }
        }
        __syncthreads();

        #pragma unroll 4
        for (int kk = 0; kk < 12; ++kk) {
            bf16x8 bfr[4];
            #pragma unroll
            for (int j = 0; j < 4; ++j)
                bfr[j] = *(const bf16x8*)(bBase[j] + kbase + kk * 32);
            bf16x8 af[4];
            #pragma unroll
            for (int i = 0; i < 4; ++i)
                af[i] = *(const bf16x8*)(aBase + i * 16 * LSTRA + kk * 32);
            #pragma unroll
            for (int i = 0; i < 4; ++i)
                #pragma unroll
                for (int j = 0; j < 4; ++j)
                    acc[i][j] = __builtin_amdgcn_mfma_f32_16x16x32_bf16(af[i], bfr[j], acc[i][j], 0, 0, 0);
        }
    }

    // ---- epilogue: transpose through LDS -> full-line bf16 stores ----
    __syncthreads();   // all A reads done; reuse sA
    unsigned short* sC = sA;
    #pragma unroll
    for (int i = 0; i < 4; ++i)
        #pragma unroll
        for (int j = 0; j < 4; ++j)
            #pragma unroll
            for (int rr = 0; rr < 4; ++rr)
                sC[(i * 16 + quad * 4 + rr) * CSTR + n0w + j * 16 + l15] = f2bf(acc[i][j][rr]);
    __syncthreads();

    const int orow = tid >> 2;        // 0..63
    const int ou   = tid & 3;         // 128 B each -> 512 B per row, coalesced
    #pragma unroll
    for (int p = 0; p < 8; ++p) {
        uint4 v = *(const uint4*)(&sC[orow * CSTR + ou * 64 + p * 8]);
        *(uint4*)(Cb + (size_t)(m0 + orow) * NCOLS + ou * 64 + p * 8) = v;
    }
}

// ---------------- kernel 2: gather-mean, block per (batch, patch-row h) ----------------
// Stage patch rows h-1 and h contiguously into LDS (coalesced), compute output rows 8h..8h+7.
__global__ __launch_bounds__(256) void gather_kernel(const unsigned short* __restrict__ proj,
                                                     float* __restrict__ out) {
    __shared__ unsigned short sPrev[64 * 256];
    __shared__ unsigned short sCur[64 * 256];

    const int blk = blockIdx.x;          // b*64 + h
    const int b   = blk >> 6;
    const int h   = blk & 63;
    const int tid = threadIdx.x;
    const unsigned short* base = proj + (size_t)b * (NPATCH * NCOLS);

    const uint4* gCur = (const uint4*)(base + (size_t)h * 64 * 256);
    #pragma unroll
    for (int p = 0; p < 8; ++p)
        ((uint4*)sCur)[tid + p * 256] = gCur[tid + p * 256];
    if (h > 0) {
        const uint4* gPrev = (const uint4*)(base + (size_t)(h - 1) * 64 * 256);
        #pragma unroll
        for (int p = 0; p < 8; ++p)
            ((uint4*)sPrev)[tid + p * 256] = gPrev[tid + p * 256];
    }
    __syncthreads();

    const int r  = tid >> 5;             // output row within block: ph = 8h + r
    const int cg = tid & 31;             // 16 pixels: pw = cg*16 .. +15
    const int ph = h * 8 + r;

    // sum of w-taps for one (row-buffer, dh, pw)
    auto tapW = [&](const unsigned short* row, int dh, int pw) -> float {
        const int w1 = pw >> 3, dw = pw & 7;
        float v = bf2f(row[w1 * 256 + dh * 16 + dw]);
        if (pw >= 8)
            v += bf2f(row[(w1 - 1) * 256 + dh * 16 + dw + 8]);
        if (pw == 511) {
            #pragma unroll
            for (int dwe = 8; dwe < 16; ++dwe)
                v += bf2f(row[63 * 256 + dh * 16 + dwe]);
        }
        return v;
    };

    const float inv_ch = (h == 0) ? 1.f : ((ph == 511) ? 0.1f : 0.5f);

    float res[16];
    #pragma unroll
    for (int j = 0; j < 16; ++j) {
        const int pw = cg * 16 + j;
        float v = tapW(sCur, r, pw);            // dh = r from patch-row h
        if (h > 0) v += tapW(sPrev, r + 8, pw); // dh = r+8 from patch-row h-1
        if (ph == 511) {                        // H-clamp extras: dh 8..15 of row 63
            #pragma unroll
            for (int dh = 8; dh < 16; ++dh) v += tapW(sCur, dh, pw);
        }
        const float inv_cw = (pw < 8) ? 1.f : ((pw == 511) ? 0.1f : 0.5f);
        res[j] = v * inv_ch * inv_cw;
    }

    float* orow = out + ((size_t)(b * 512 + ph)) * 512 + cg * 16;
    #pragma unroll
    for (int q = 0; q < 4; ++q)
        *(float4*)(orow + q * 4) = make_float4(res[4 * q], res[4 * q + 1], res[4 * q + 2], res[4 * q + 3]);
}

extern "C" void kernel_launch(void* const* d_in, const int* in_sizes, int n_in,
                              void* d_out, int out_size, void* d_ws, size_t ws_size,
                              hipStream_t stream) {
    const float* tgt    = (const float*)d_in[0];   // [16,4096,768] fp32
    const float* weight = (const float*)d_in[1];   // [16,16,768]  fp32
    float* out = (float*)d_out;                    // [16,512,512] fp32

    unsigned short* proj = (unsigned short*)d_ws;                                      // 32 MB bf16
    unsigned short* wbf  = (unsigned short*)((char*)d_ws + (size_t)MROWS * NCOLS * 2); // +384 KB

    wconv_kernel<<<192, 256, 0, stream>>>(weight, wbf);
    gemm_kernel<<<MROWS / 64, 256, 0, stream>>>(tgt, wbf, proj);         // 1024 blocks
    gather_kernel<<<BATCH * 64, 256, 0, stream>>>(proj, out);            // 1024 blocks
}